// Round 8
// baseline (171.685 us; speedup 1.0000x reference)
//
#include <hip/hip_runtime.h>
#include <math.h>

#define S_LEN 8192
#define DHEAD 64
#define NBATCH 4
#define BK 32
#define KIT 64            // 2048 keys per kq-quarter / BK

typedef unsigned short u16;
typedef unsigned int u32;
typedef __attribute__((ext_vector_type(8))) short short8;
typedef __attribute__((ext_vector_type(8))) _Float16 half8;
typedef __attribute__((ext_vector_type(2))) __fp16 fp16x2;
typedef __attribute__((ext_vector_type(4))) float f32x4;

union U16x8 { int4 i4; short8 s8; u32 w[4]; };
union HU8  { int4 i4; half8 h8; u32 w[4]; };
union H2U  { fp16x2 h2; u32 w; };
union HU   { _Float16 h; u16 u; };

#if __has_builtin(__builtin_amdgcn_exp2f)
#define EXP2(x) __builtin_amdgcn_exp2f(x)
#else
#define EXP2(x) exp2f(x)
#endif

// float -> bf16 RNE (prep path only)
__device__ __forceinline__ u16 f2b(float f) {
    u32 u = __float_as_uint(f);
    u32 r = (u + 0x7fffu + ((u >> 16) & 1u)) >> 16;
    return (u16)r;
}
// float -> f16 RNE (prep path only)
__device__ __forceinline__ u16 f2h(float f) {
    HU x; x.h = (_Float16)f; return x.u;
}
// two floats -> packed f16x2, single v_cvt_pkrtz_f16_f32
__device__ __forceinline__ u32 packh2(float a, float b) {
    H2U x; x.h2 = __builtin_amdgcn_cvt_pkrtz(a, b); return x.w;
}

// ---------------------------------------------------------------------------
// Prep: blocks [0,1024) pack K (bf16) and V (f16) of one 32-key tile
// (b = bid>>8, t = bid&255) into MFMA-fragment order:
//   blob[b][t] (8 KB) = K chunks j=0..3 (j=kt*2+ds) then V chunks dt=0..3,
//   chunk = 64 lanes x 16 B, exact flash lane order:
//     K: lane(low,h) -> K[b][t*32 + 8*(low>>2)+4*kt+(low&3)][ds*32+h*8+0..7]
//     V: lane(low,h) -> V[b][t*32 + h*8 + 0..7][dt*16+low]   (f16)
// Blocks [1024,1056): Julia bias in f64 (matches numpy), fixed max M=20
// folded: bias2[k] = log(exp(et*scale)+1e-8)*log2e - 20.
// ---------------------------------------------------------------------------
__global__ void prep_kernel(const float* __restrict__ K, const float* __restrict__ V,
                            const float* crp, const float* cip, const float* scp,
                            u16* __restrict__ blob, float* __restrict__ bias2) {
    int bid = blockIdx.x, tid = threadIdx.x;
    if (bid < 1024) {
        int b = bid >> 8, t = bid & 255;
        __shared__ float Kt[32 * 64];
        __shared__ float Vt[32 * 65];          // padded rows: conflict-free col reads
        int row = tid >> 3, c8 = (tid & 7) * 8;
        const float* ks = K + ((size_t)(b * S_LEN + t * 32 + row)) * 64 + c8;
        const float* vs = V + ((size_t)(b * S_LEN + t * 32 + row)) * 64 + c8;
        float4 ka = *(const float4*)ks, kb4 = *(const float4*)(ks + 4);
        float4 va = *(const float4*)vs, vb4 = *(const float4*)(vs + 4);
        *(float4*)&Kt[row * 64 + c8] = ka;
        *(float4*)&Kt[row * 64 + c8 + 4] = kb4;
        float* vr = &Vt[row * 65 + c8];
        vr[0] = va.x; vr[1] = va.y; vr[2] = va.z; vr[3] = va.w;
        vr[4] = vb4.x; vr[5] = vb4.y; vr[6] = vb4.z; vr[7] = vb4.w;
        __syncthreads();

        int j = tid >> 6, lane = tid & 63, low = lane & 15, h = lane >> 4;
        u16* tb = blob + ((size_t)(b * 256 + t)) * 4096;   // u16 elems (8 KB)
        {   // K chunk j = kt*2 + ds  (bf16)
            int kt = j >> 1, ds = j & 1;
            int krow = 8 * (low >> 2) + 4 * kt + (low & 3);
            const float* src = &Kt[krow * 64 + ds * 32 + h * 8];
            u32 wds[4];
#pragma unroll
            for (int i = 0; i < 4; ++i)
                wds[i] = (u32)f2b(src[2 * i]) | ((u32)f2b(src[2 * i + 1]) << 16);
            *(int4*)(tb + j * 512 + lane * 8) = make_int4(wds[0], wds[1], wds[2], wds[3]);
        }
        {   // V chunk dt = j  (f16)
            int col = j * 16 + low;
            u32 wds[4];
#pragma unroll
            for (int i = 0; i < 4; ++i) {
                float a = Vt[(h * 8 + 2 * i) * 65 + col];
                float c = Vt[(h * 8 + 2 * i + 1) * 65 + col];
                wds[i] = (u32)f2h(a) | ((u32)f2h(c) << 16);
            }
            *(int4*)(tb + 2048 + j * 512 + lane * 8) = make_int4(wds[0], wds[1], wds[2], wds[3]);
        }
    } else {
#pragma clang fp contract(off)
        int i = (bid - 1024) * 256 + tid;
        double cr = (double)crp[0], ci = (double)cip[0], sc = (double)scp[0];
        double step = 4.0 / (double)(S_LEN - 1);
        double x = (i == S_LEN - 1) ? 2.0 : (-2.0 + step * (double)i);
        double zr = x, zi = 0.0, et = 1.0;
        bool esc = false;
        for (int it = 0; it < 64; ++it) {
            double nzr = zr * zr - zi * zi + cr;
            double nzi = 2.0 * zr * zi + ci;
            if (!esc) { zr = nzr; zi = nzi; }
            double m2 = zr * zr + zi * zi;
            if (!esc && m2 > 4.0) { et = (double)it / 64.0; esc = true; }
        }
        double bias = log(exp(et * sc) + 1e-8);
        bias2[i] = (float)(bias * 1.4426950408889634 - 20.0);
    }
}

// ---------------------------------------------------------------------------
// Flash: packed-fragment streaming, no LDS / no barriers in the main loop.
//   grid 512 (2 blocks/CU), block 512 = 8 waves = 4 kq x 2 qs; wave = 32 q x
//   2048 keys, BK=32. K-frags + bias register-double-buffered (prefetched one
//   iter ahead); V single-buffered (consumed late). P packed to f16 via
//   cvt_pkrtz; PV in mfma_f32_16x16x32_f16. Fixed-max softmax (M=20 in bias);
//   split-K merge by plain adds at the end.
// ---------------------------------------------------------------------------
__global__ __launch_bounds__(512, 4)
void flash_kernel(const float* __restrict__ Q, const u16* __restrict__ blob,
                  const float* __restrict__ bias2, float* __restrict__ Out) {
    __shared__ __align__(16) char smem[18432];   // merge scratch only

    const int tid = threadIdx.x;
    const int l = tid & 63, low = l & 15, h = l >> 4;
    const int kq = __builtin_amdgcn_readfirstlane((tid >> 6) & 3);
    const int qs = __builtin_amdgcn_readfirstlane(tid >> 8);

    const int bid = blockIdx.x;
    const int batch = bid & 3;          // XCD-affinity: batch b on XCDs {b, b+4}
    const int qtile = bid >> 2;         // 0..127 (BQ = 64)
    const int q0 = qtile * 64 + qs * 32;

    // ---- Q fragments (2 x 16 q-rows), scale log2(e)/8 folded ----
    const float qscale = 0.18033688011112042f;
    short8 qfrag[2][2];
#pragma unroll
    for (int qf = 0; qf < 2; ++qf) {
        const float* qrow = Q + ((size_t)(batch * S_LEN + q0 + qf * 16 + low)) * DHEAD + h * 8;
#pragma unroll
        for (int ds = 0; ds < 2; ++ds) {
            f32x4 a = *(const f32x4*)(qrow + ds * 32);
            f32x4 b = *(const f32x4*)(qrow + ds * 32 + 4);
            U16x8 u;
#pragma unroll
            for (int jj = 0; jj < 4; ++jj) {
                u.s8[jj]     = (short)f2b(a[jj] * qscale);
                u.s8[4 + jj] = (short)f2b(b[jj] * qscale);
            }
            qfrag[qf][ds] = u.s8;
        }
    }

    // wave-uniform stream base (SGPR) + single lane offset (VGPR)
    const u16* kvb = blob + ((size_t)(batch * 256 + kq * 64)) * 4096;
    const int loff = l * 8;                         // u16 elems (16 B/lane)
    const float* bbase = bias2 + kq * 2048;

    f32x4 o[2][4];
#pragma unroll
    for (int qf = 0; qf < 2; ++qf)
#pragma unroll
        for (int dt = 0; dt < 4; ++dt) o[qf][dt] = (f32x4){0, 0, 0, 0};
    float lsum[2] = {0.f, 0.f};

    // ---- K + bias register double-buffer: preload iter 0 ----
    U16x8 kf[2][4];
    f32x4 bvv[2][2];
#pragma unroll
    for (int j = 0; j < 4; ++j) kf[0][j].i4 = *(const int4*)(kvb + j * 512 + loff);
    bvv[0][0] = *(const f32x4*)(bbase + h * 8);
    bvv[0][1] = *(const f32x4*)(bbase + h * 8 + 4);

#pragma unroll 2
    for (int ki = 0; ki < KIT; ++ki) {
        const int c = ki & 1;
        const u16* tb = kvb + ki * 4096;

        // V frags for THIS iter (consumed after softmax -> latency covered)
        HU8 vf[4];
#pragma unroll
        for (int j = 0; j < 4; ++j) vf[j].i4 = *(const int4*)(tb + 2048 + j * 512 + loff);

        // prefetch NEXT iter's K frags + bias (blob has 8 KB tail pad)
        const u16* tn = tb + 4096;
#pragma unroll
        for (int j = 0; j < 4; ++j) kf[c ^ 1][j].i4 = *(const int4*)(tn + j * 512 + loff);
        const float* bpn = bbase + (ki + 1) * 32 + h * 8;
        bvv[c ^ 1][0] = *(const f32x4*)bpn;
        bvv[c ^ 1][1] = *(const f32x4*)(bpn + 4);

        // ---- per-kt: QK (bias as C-init) then softmax (short st liveness) ----
        HU8 pf[2];
#pragma unroll
        for (int kt = 0; kt < 2; ++kt) {
            const f32x4 binit = kt ? bvv[c][1] : bvv[c][0];
            f32x4 st[2];
#pragma unroll
            for (int qf = 0; qf < 2; ++qf) {
                f32x4 a = __builtin_amdgcn_mfma_f32_16x16x32_bf16(kf[c][kt * 2].s8, qfrag[qf][0], binit, 0, 0, 0);
                a = __builtin_amdgcn_mfma_f32_16x16x32_bf16(kf[c][kt * 2 + 1].s8, qfrag[qf][1], a, 0, 0, 0);
                st[qf] = a;
            }
#pragma unroll
            for (int qf = 0; qf < 2; ++qf) {
                float p0 = EXP2(st[qf][0]), p1 = EXP2(st[qf][1]);
                float p2 = EXP2(st[qf][2]), p3 = EXP2(st[qf][3]);
                lsum[qf] += (p0 + p1) + (p2 + p3);
                pf[qf].w[kt * 2]     = packh2(p0, p1);
                pf[qf].w[kt * 2 + 1] = packh2(p2, p3);
            }
        }

        // ---- O^T += V^T·P^T (f16, K=32), V-frag shared across q-frags ----
#pragma unroll
        for (int dt = 0; dt < 4; ++dt)
#pragma unroll
            for (int qf = 0; qf < 2; ++qf)
                o[qf][dt] = __builtin_amdgcn_mfma_f32_16x16x32_f16(vf[dt].h8, pf[qf].h8, o[qf][dt], 0, 0, 0);
    }

    // ---- finalize l ----
#pragma unroll
    for (int qf = 0; qf < 2; ++qf) {
        lsum[qf] += __shfl_xor(lsum[qf], 16, 64);
        lsum[qf] += __shfl_xor(lsum[qf], 32, 64);
    }

    // ---- split-K merge: partials add linearly (fixed max). 3 stages. ----
    float* MO = (float*)smem;              // [64][68]
    float* ML = (float*)(smem + 17408);    // [64]
    const int baserow = qs * 32 + low;
#pragma unroll 1
    for (int src = 1; src < 4; ++src) {
        __syncthreads();
        if (kq == src) {
#pragma unroll
            for (int qf = 0; qf < 2; ++qf) {
                const int row = baserow + qf * 16;
#pragma unroll
                for (int dt = 0; dt < 4; ++dt)
                    *(f32x4*)&MO[row * 68 + dt * 16 + h * 4] = o[qf][dt];
                if (h == 0) ML[row] = lsum[qf];
            }
        }
        __syncthreads();
        if (kq == 0) {
#pragma unroll
            for (int qf = 0; qf < 2; ++qf) {
                const int row = baserow + qf * 16;
#pragma unroll
                for (int dt = 0; dt < 4; ++dt) {
                    f32x4 a = *(const f32x4*)&MO[row * 68 + dt * 16 + h * 4];
#pragma unroll
                    for (int jj = 0; jj < 4; ++jj) o[qf][dt][jj] += a[jj];
                }
                lsum[qf] += ML[row];
            }
        }
    }

    if (kq == 0) {
#pragma unroll
        for (int qf = 0; qf < 2; ++qf) {
            const float inv = 1.f / lsum[qf];
            float* orow = Out + ((size_t)(batch * S_LEN + qtile * 64 + qs * 32 + qf * 16 + low)) * DHEAD;
#pragma unroll
            for (int dt = 0; dt < 4; ++dt) {
                f32x4 r;
#pragma unroll
                for (int jj = 0; jj < 4; ++jj) r[jj] = o[qf][dt][jj] * inv;
                *(f32x4*)(orow + dt * 16 + h * 4) = r;
            }
        }
    }
}

// ---------------------------------------------------------------------------
extern "C" void kernel_launch(void* const* d_in, const int* in_sizes, int n_in,
                              void* d_out, int out_size, void* d_ws, size_t ws_size,
                              hipStream_t stream) {
    const float* Q  = (const float*)d_in[0];
    const float* K  = (const float*)d_in[1];
    const float* V  = (const float*)d_in[2];
    const float* cr = (const float*)d_in[3];
    const float* ci = (const float*)d_in[4];
    const float* sc = (const float*)d_in[5];
    float* out = (float*)d_out;

    char* ws = (char*)d_ws;
    float* bias2 = (float*)ws;                 // 32 KB
    u16*   blob  = (u16*)(ws + 32768);         // 8 MB packed K+V frags (+8 KB pad)

    prep_kernel<<<dim3(1056), dim3(256), 0, stream>>>(K, V, cr, ci, sc, blob, bias2);
    flash_kernel<<<dim3(512), dim3(512), 0, stream>>>(Q, blob, bias2, out);
}

// Round 9
// 149.683 us; speedup vs baseline: 1.1470x; 1.1470x over previous
//
#include <hip/hip_runtime.h>
#include <math.h>

#define S_LEN 8192
#define DHEAD 64
#define NBATCH 4
#define BK 32
#define KIT 64            // 2048 keys per kq-quarter / BK

typedef unsigned short u16;
typedef unsigned int u32;
typedef __attribute__((ext_vector_type(8))) _Float16 half8;
typedef __attribute__((ext_vector_type(2))) __fp16 fp16x2;
typedef __attribute__((ext_vector_type(4))) float f32x4;

union HU8 { int4 i4; half8 h8; u32 w[4]; };
union H2U { fp16x2 h2; u32 w; };
union HU  { _Float16 h; u16 u; };

#if __has_builtin(__builtin_amdgcn_exp2f)
#define EXP2(x) __builtin_amdgcn_exp2f(x)
#else
#define EXP2(x) exp2f(x)
#endif

// float -> f16 RNE
__device__ __forceinline__ u16 f2h(float f) {
    HU x; x.h = (_Float16)f; return x.u;
}
// two floats -> packed f16x2, single v_cvt_pkrtz_f16_f32
__device__ __forceinline__ u32 packh2(float a, float b) {
    H2U x; x.h2 = __builtin_amdgcn_cvt_pkrtz(a, b); return x.w;
}

// ---------------------------------------------------------------------------
// Prep: blocks [0,1024) pack K and V (both f16) of one 32-key tile
// (b = bid>>8, t = bid&255) into MFMA-fragment order:
//   blob[b][t] (8 KB) = K chunks j=0..3 (j=kt*2+ds) then V chunks dt=0..3,
//   chunk = 64 lanes x 16 B, exact flash lane order:
//     K: lane(low,h) -> K[b][t*32 + 8*(low>>2)+4*kt+(low&3)][ds*32+h*8+0..7]
//     V: lane(low,h) -> V[b][t*32 + h*8 + 0..7][dt*16+low]
// Blocks [1024,1056): Julia bias in f64 (matches numpy), fixed max M=20
// folded: bias2[k] = log(exp(et*scale)+1e-8)*log2e - 20.
// ---------------------------------------------------------------------------
__global__ void prep_kernel(const float* __restrict__ K, const float* __restrict__ V,
                            const float* crp, const float* cip, const float* scp,
                            u16* __restrict__ blob, float* __restrict__ bias2) {
    int bid = blockIdx.x, tid = threadIdx.x;
    if (bid < 1024) {
        int b = bid >> 8, t = bid & 255;
        __shared__ float Kt[32 * 64];
        __shared__ float Vt[32 * 65];          // padded rows: conflict-free col reads
        int row = tid >> 3, c8 = (tid & 7) * 8;
        const float* ks = K + ((size_t)(b * S_LEN + t * 32 + row)) * 64 + c8;
        const float* vs = V + ((size_t)(b * S_LEN + t * 32 + row)) * 64 + c8;
        float4 ka = *(const float4*)ks, kb4 = *(const float4*)(ks + 4);
        float4 va = *(const float4*)vs, vb4 = *(const float4*)(vs + 4);
        *(float4*)&Kt[row * 64 + c8] = ka;
        *(float4*)&Kt[row * 64 + c8 + 4] = kb4;
        float* vr = &Vt[row * 65 + c8];
        vr[0] = va.x; vr[1] = va.y; vr[2] = va.z; vr[3] = va.w;
        vr[4] = vb4.x; vr[5] = vb4.y; vr[6] = vb4.z; vr[7] = vb4.w;
        __syncthreads();

        int j = tid >> 6, lane = tid & 63, low = lane & 15, h = lane >> 4;
        u16* tb = blob + ((size_t)(b * 256 + t)) * 4096;   // u16 elems (8 KB)
        {   // K chunk j = kt*2 + ds  (f16)
            int kt = j >> 1, ds = j & 1;
            int krow = 8 * (low >> 2) + 4 * kt + (low & 3);
            const float* src = &Kt[krow * 64 + ds * 32 + h * 8];
            u32 wds[4];
#pragma unroll
            for (int i = 0; i < 4; ++i)
                wds[i] = (u32)f2h(src[2 * i]) | ((u32)f2h(src[2 * i + 1]) << 16);
            *(int4*)(tb + j * 512 + lane * 8) = make_int4(wds[0], wds[1], wds[2], wds[3]);
        }
        {   // V chunk dt = j  (f16)
            int col = j * 16 + low;
            u32 wds[4];
#pragma unroll
            for (int i = 0; i < 4; ++i) {
                float a = Vt[(h * 8 + 2 * i) * 65 + col];
                float c = Vt[(h * 8 + 2 * i + 1) * 65 + col];
                wds[i] = (u32)f2h(a) | ((u32)f2h(c) << 16);
            }
            *(int4*)(tb + 2048 + j * 512 + lane * 8) = make_int4(wds[0], wds[1], wds[2], wds[3]);
        }
    } else {
#pragma clang fp contract(off)
        int i = (bid - 1024) * 256 + tid;
        double cr = (double)crp[0], ci = (double)cip[0], sc = (double)scp[0];
        double step = 4.0 / (double)(S_LEN - 1);
        double x = (i == S_LEN - 1) ? 2.0 : (-2.0 + step * (double)i);
        double zr = x, zi = 0.0, et = 1.0;
        bool esc = false;
        for (int it = 0; it < 64; ++it) {
            double nzr = zr * zr - zi * zi + cr;
            double nzi = 2.0 * zr * zi + ci;
            if (!esc) { zr = nzr; zi = nzi; }
            double m2 = zr * zr + zi * zi;
            if (!esc && m2 > 4.0) { et = (double)it / 64.0; esc = true; }
        }
        double bias = log(exp(et * sc) + 1e-8);
        bias2[i] = (float)(bias * 1.4426950408889634 - 20.0);
    }
}

// ---------------------------------------------------------------------------
// Flash: packed-fragment streaming, no LDS / no barriers in the main loop.
//   grid 512 (2 blocks/CU), block 256 = 4 waves = 4 kq; each wave covers the
//   block's 64 q-rows (4 q-frags) x its 2048-key quarter, BK=32, 64 iters.
//   64 q/wave halves L1 traffic vs R8 (frag loads amortized over 4 q-frags).
//   K+bias register-double-buffered; V single-buffered (consumed late).
//   All operands f16 (K,Q,V,P); fixed-max softmax (M=20 folded into bias);
//   4-way split-K merged by plain adds through LDS at the end.
// ---------------------------------------------------------------------------
__global__ __launch_bounds__(256, 2)
void flash_kernel(const float* __restrict__ Q, const u16* __restrict__ blob,
                  const float* __restrict__ bias2, float* __restrict__ Out) {
    __shared__ __align__(16) char smem[17664];   // merge scratch only

    const int tid = threadIdx.x;
    const int l = tid & 63, low = l & 15, h = l >> 4;
    const int kq = __builtin_amdgcn_readfirstlane(tid >> 6);

    const int bid = blockIdx.x;
    const int batch = bid & 3;          // XCD-affinity: batch b on XCDs {b, b+4}
    const int qtile = bid >> 2;         // 0..127 (BQ = 64)
    const int q0 = qtile * 64;

    // ---- Q fragments (4 x 16 q-rows, f16), scale log2(e)/8 folded ----
    const float qscale = 0.18033688011112042f;
    half8 qfrag[4][2];
#pragma unroll
    for (int qf = 0; qf < 4; ++qf) {
        const float* qrow = Q + ((size_t)(batch * S_LEN + q0 + qf * 16 + low)) * DHEAD + h * 8;
#pragma unroll
        for (int ds = 0; ds < 2; ++ds) {
            f32x4 a = *(const f32x4*)(qrow + ds * 32);
            f32x4 b = *(const f32x4*)(qrow + ds * 32 + 4);
            HU8 u;
            u.w[0] = packh2(a[0] * qscale, a[1] * qscale);
            u.w[1] = packh2(a[2] * qscale, a[3] * qscale);
            u.w[2] = packh2(b[0] * qscale, b[1] * qscale);
            u.w[3] = packh2(b[2] * qscale, b[3] * qscale);
            qfrag[qf][ds] = u.h8;
        }
    }

    // wave-uniform stream base (SGPR) + single lane offset (VGPR)
    const u16* kvb = blob + ((size_t)(batch * 256 + kq * 64)) * 4096;
    const int loff = l * 8;                         // u16 elems (16 B/lane)
    const float* bbase = bias2 + kq * 2048;

    f32x4 o[4][4];
#pragma unroll
    for (int qf = 0; qf < 4; ++qf)
#pragma unroll
        for (int dt = 0; dt < 4; ++dt) o[qf][dt] = (f32x4){0, 0, 0, 0};
    float lsum[4] = {0.f, 0.f, 0.f, 0.f};

    // ---- K + bias register double-buffer: preload iter 0 ----
    HU8 kf[2][4];
    f32x4 bvv[2][2];
#pragma unroll
    for (int j = 0; j < 4; ++j) kf[0][j].i4 = *(const int4*)(kvb + j * 512 + loff);
    bvv[0][0] = *(const f32x4*)(bbase + h * 8);
    bvv[0][1] = *(const f32x4*)(bbase + h * 8 + 4);

#pragma unroll 2
    for (int ki = 0; ki < KIT; ++ki) {
        const int c = ki & 1;
        const u16* tb = kvb + ki * 4096;

        // V frags for THIS iter (consumed after softmax -> latency covered)
        HU8 vf[4];
#pragma unroll
        for (int j = 0; j < 4; ++j) vf[j].i4 = *(const int4*)(tb + 2048 + j * 512 + loff);

        // prefetch NEXT iter's K frags + bias (blob has 8 KB tail pad)
        const u16* tn = tb + 4096;
#pragma unroll
        for (int j = 0; j < 4; ++j) kf[c ^ 1][j].i4 = *(const int4*)(tn + j * 512 + loff);
        const float* bpn = bbase + (ki + 1) * 32 + h * 8;
        bvv[c ^ 1][0] = *(const f32x4*)bpn;
        bvv[c ^ 1][1] = *(const f32x4*)(bpn + 4);

        // ---- per-kt: QK (bias as C-init) then softmax (short st liveness) ----
        HU8 pf[4];
#pragma unroll
        for (int kt = 0; kt < 2; ++kt) {
            const f32x4 binit = kt ? bvv[c][1] : bvv[c][0];
            f32x4 st[4];
#pragma unroll
            for (int qf = 0; qf < 4; ++qf) {
                f32x4 a = __builtin_amdgcn_mfma_f32_16x16x32_f16(kf[c][kt * 2].h8, qfrag[qf][0], binit, 0, 0, 0);
                a = __builtin_amdgcn_mfma_f32_16x16x32_f16(kf[c][kt * 2 + 1].h8, qfrag[qf][1], a, 0, 0, 0);
                st[qf] = a;
            }
#pragma unroll
            for (int qf = 0; qf < 4; ++qf) {
                float p0 = EXP2(st[qf][0]), p1 = EXP2(st[qf][1]);
                float p2 = EXP2(st[qf][2]), p3 = EXP2(st[qf][3]);
                lsum[qf] += (p0 + p1) + (p2 + p3);
                pf[qf].w[kt * 2]     = packh2(p0, p1);
                pf[qf].w[kt * 2 + 1] = packh2(p2, p3);
            }
        }

        // ---- O^T += V^T·P^T (f16, K=32), V-frag shared across 4 q-frags ----
#pragma unroll
        for (int dt = 0; dt < 4; ++dt)
#pragma unroll
            for (int qf = 0; qf < 4; ++qf)
                o[qf][dt] = __builtin_amdgcn_mfma_f32_16x16x32_f16(vf[dt].h8, pf[qf].h8, o[qf][dt], 0, 0, 0);
    }

    // ---- finalize l ----
#pragma unroll
    for (int qf = 0; qf < 4; ++qf) {
        lsum[qf] += __shfl_xor(lsum[qf], 16, 64);
        lsum[qf] += __shfl_xor(lsum[qf], 32, 64);
    }

    // ---- split-K merge: partials add linearly (fixed max). 3 stages. ----
    float* MO = (float*)smem;              // [64][68]
    float* ML = (float*)(smem + 17408);    // [64]
#pragma unroll 1
    for (int src = 1; src < 4; ++src) {
        __syncthreads();
        if (kq == src) {
#pragma unroll
            for (int qf = 0; qf < 4; ++qf) {
                const int row = qf * 16 + low;
#pragma unroll
                for (int dt = 0; dt < 4; ++dt)
                    *(f32x4*)&MO[row * 68 + dt * 16 + h * 4] = o[qf][dt];
                if (h == 0) ML[row] = lsum[qf];
            }
        }
        __syncthreads();
        if (kq == 0) {
#pragma unroll
            for (int qf = 0; qf < 4; ++qf) {
                const int row = qf * 16 + low;
#pragma unroll
                for (int dt = 0; dt < 4; ++dt) {
                    f32x4 a = *(const f32x4*)&MO[row * 68 + dt * 16 + h * 4];
#pragma unroll
                    for (int jj = 0; jj < 4; ++jj) o[qf][dt][jj] += a[jj];
                }
                lsum[qf] += ML[row];
            }
        }
    }

    if (kq == 0) {
#pragma unroll
        for (int qf = 0; qf < 4; ++qf) {
            const float inv = 1.f / lsum[qf];
            float* orow = Out + ((size_t)(batch * S_LEN + q0 + qf * 16 + low)) * DHEAD;
#pragma unroll
            for (int dt = 0; dt < 4; ++dt) {
                f32x4 r;
#pragma unroll
                for (int jj = 0; jj < 4; ++jj) r[jj] = o[qf][dt][jj] * inv;
                *(f32x4*)(orow + dt * 16 + h * 4) = r;
            }
        }
    }
}

// ---------------------------------------------------------------------------
extern "C" void kernel_launch(void* const* d_in, const int* in_sizes, int n_in,
                              void* d_out, int out_size, void* d_ws, size_t ws_size,
                              hipStream_t stream) {
    const float* Q  = (const float*)d_in[0];
    const float* K  = (const float*)d_in[1];
    const float* V  = (const float*)d_in[2];
    const float* cr = (const float*)d_in[3];
    const float* ci = (const float*)d_in[4];
    const float* sc = (const float*)d_in[5];
    float* out = (float*)d_out;

    char* ws = (char*)d_ws;
    float* bias2 = (float*)ws;                 // 32 KB
    u16*   blob  = (u16*)(ws + 32768);         // 8 MB packed K+V frags (+8 KB pad)

    prep_kernel<<<dim3(1056), dim3(256), 0, stream>>>(K, V, cr, ci, sc, blob, bias2);
    flash_kernel<<<dim3(512), dim3(256), 0, stream>>>(Q, blob, bias2, out);
}